// Round 16
// baseline (524.400 us; speedup 1.0000x reference)
//
#include <hip/hip_runtime.h>

constexpr int HW  = 6400;   // 80*80
constexpr int WW  = 80;

typedef __attribute__((ext_vector_type(8))) short short8;   // 8 bf16 = 4 VGPR
typedef __attribute__((ext_vector_type(4))) float f32x4;
typedef unsigned short ushort_t;

__device__ __forceinline__ float sigmoidf_(float x) { return 1.f / (1.f + __expf(-x)); }
__device__ __forceinline__ float siluf_(float y) { return y / (1.f + __expf(-y)); }
__device__ __forceinline__ ushort_t f2bf(float f) {   // RNE f32->bf16
    unsigned u = __float_as_uint(f);
    u += 0x7FFFu + ((u >> 16) & 1u);
    return (ushort_t)(u >> 16);
}
__device__ __forceinline__ float bf2f(ushort_t h) {
    return __uint_as_float(((unsigned)h) << 16);
}
// XCD-affinity swizzle for 800-block grids (800 = 8 XCDs x 100): block
// blockIdx.x lands on XCD (blockIdx.x % 8); remap so XCD k owns contiguous
// bid range = batch image k. Verified r14: k3 FETCH 40 MB -> 13.6 MB.
__device__ __forceinline__ int xcd_bid800(int b) { return (b & 7) * 100 + (b >> 3); }

// bilinear blend of 4 corner uint4s (8 bf16 ch each) -> packed bf16 short8
__device__ __forceinline__ short8 blend8(const float4 w,
    const uint4 A, const uint4 B, const uint4 C, const uint4 D)
{
    const unsigned* ap = (const unsigned*)&A;
    const unsigned* bp = (const unsigned*)&B;
    const unsigned* cp = (const unsigned*)&C;
    const unsigned* dp = (const unsigned*)&D;
    unsigned r[4];
#pragma unroll
    for (int u = 0; u < 4; ++u) {
        const float alo = __uint_as_float(ap[u] << 16), ahi = __uint_as_float(ap[u] & 0xFFFF0000u);
        const float blo = __uint_as_float(bp[u] << 16), bhi = __uint_as_float(bp[u] & 0xFFFF0000u);
        const float clo = __uint_as_float(cp[u] << 16), chi = __uint_as_float(cp[u] & 0xFFFF0000u);
        const float dlo = __uint_as_float(dp[u] << 16), dhi = __uint_as_float(dp[u] & 0xFFFF0000u);
        const float slo = w.x * alo + w.y * blo + w.z * clo + w.w * dlo;
        const float shi = w.x * ahi + w.y * bhi + w.z * chi + w.w * dhi;
        r[u] = (unsigned)f2bf(slo) | ((unsigned)f2bf(shi) << 16);
    }
    uint4 pk = make_uint4(r[0], r[1], r[2], r[3]);
    return *reinterpret_cast<short8*>(&pk);
}

// ---------------------------------------------------------------------------
// k0: weight prep (bf16 MFMA fragment layouts)
// ---------------------------------------------------------------------------
__global__ __launch_bounds__(256) void k0_prep(
    const float* __restrict__ rw, const float* __restrict__ ow,
    const float* __restrict__ dw,
    const float* __restrict__ rg, const float* __restrict__ rb,
    const float* __restrict__ rm, const float* __restrict__ rv,
    ushort_t* __restrict__ WB,
    ushort_t* __restrict__ WoB, ushort_t* __restrict__ WdB,
    float* __restrict__ scr, float* __restrict__ shr)
{
    const int i = blockIdx.x * 256 + threadIdx.x;
    if (blockIdx.x == 0 && threadIdx.x < 128) {
        const int m = threadIdx.x;
        const float sc = rg[m] * rsqrtf(rv[m] + 1e-5f);
        scr[m] = sc;
        shr[m] = rb[m] - rm[m] * sc;
    }
    if (i < 65536) {                       // WB: 128 chunks * 512
        const int e = i & 7;
        const int lane = (i >> 3) & 63;
        const int chunkW = i >> 9;         // 0..127
        const int nt = chunkW >> 4, kks = chunkW & 15;
        const int kk = kks * 32 + ((lane >> 4) << 3) + e;   // cs 0..511
        const int o = (nt << 4) + (lane & 15);              // out ch 0..127
        WB[i] = f2bf(rw[o * 512 + kk]);
    }
    const int j = i - 65536;
    if (j >= 0 && j < 36864) {             // WoB: 2*36*512
        const int e = j & 7;
        const int lane = (j >> 3) & 63;
        const int chunk = j >> 9;
        const int nf = chunk / 36, ksg = chunk % 36;
        const int kk = ksg * 32 + ((lane >> 4) << 3) + e;
        const int q = kk >> 7, c = kk & 127;
        const int o = (nf << 4) + (lane & 15);
        WoB[j] = (o < 27) ? f2bf(ow[o * 1152 + c * 9 + q]) : (ushort_t)0;
    }
    const int l = j - 36864;
    if (l >= 0 && l < 294912) {            // WdB: 16*36*512
        const int e = l & 7;
        const int lane = (l >> 3) & 63;
        const int chunk = l >> 9;
        const int ot = chunk / 36, ksg = chunk % 36;
        const int kk = ksg * 32 + ((lane >> 4) << 3) + e;
        const int tap = kk >> 7, c = kk & 127;
        const int o = (ot << 4) + (lane & 15);
        WdB[l] = f2bf(dw[o * 1152 + c * 9 + tap]);
    }
}

// ---------------------------------------------------------------------------
// k1 v3: space-to-depth + 1x1 conv as bf16 MFMA, NO LDS. XCD-affine blocks.
// ---------------------------------------------------------------------------
__global__ __launch_bounds__(256) void k1_reduce(
    const float* __restrict__ x,
    const ushort_t* __restrict__ WB,
    const float* __restrict__ scr, const float* __restrict__ shr,
    ushort_t* __restrict__ xm_bf)
{
    const int t    = threadIdx.x;
    const int lane = t & 63;
    const int wave = t >> 6;
    const int q = lane >> 4, ln = lane & 15;
    const int p0 = xcd_bid800(blockIdx.x) * 64;
    const int bb = p0 / HW;
    const int px = wave * 16 + ln;
    const int hw = (p0 % HW) + px;
    const int h = hw / WW, w = hw % WW;
    const float* xb = x + (size_t)bb * 128 * 25600 + (2 * h) * 160 + 2 * w;

    f32x4 acc[8] = {};

#pragma unroll 4
    for (int kks = 0; kks < 16; ++kks) {
        const int c0 = kks * 8 + q * 2;       // 2 channels per fragment
        const float* pc0 = xb + (size_t)c0 * 25600;
        const float* pc1 = pc0 + 25600;
        const float2 a0 = *reinterpret_cast<const float2*>(pc0);
        const float2 a1 = *reinterpret_cast<const float2*>(pc0 + 160);
        const float2 b0 = *reinterpret_cast<const float2*>(pc1);
        const float2 b1 = *reinterpret_cast<const float2*>(pc1 + 160);
        short8 p;
        p[0] = (short)f2bf(a0.x); p[1] = (short)f2bf(a0.y);
        p[2] = (short)f2bf(a1.x); p[3] = (short)f2bf(a1.y);
        p[4] = (short)f2bf(b0.x); p[5] = (short)f2bf(b0.y);
        p[6] = (short)f2bf(b1.x); p[7] = (short)f2bf(b1.y);
#pragma unroll
        for (int nt = 0; nt < 8; ++nt) {
            const short8 wf = *reinterpret_cast<const short8*>(WB + ((nt << 4) + kks) * 512 + lane * 8);
            acc[nt] = __builtin_amdgcn_mfma_f32_16x16x32_bf16(wf, p, acc[nt], 0, 0, 0);
        }
    }

    const int pi = p0 + px;
    ushort_t* op = xm_bf + (size_t)pi * 128;
#pragma unroll
    for (int nt = 0; nt < 8; ++nt) {
        const int ob = nt * 16 + q * 4;
        const float4 s4 = *reinterpret_cast<const float4*>(scr + ob);
        const float4 b4 = *reinterpret_cast<const float4*>(shr + ob);
        const float y0 = siluf_(acc[nt][0] * s4.x + b4.x);
        const float y1 = siluf_(acc[nt][1] * s4.y + b4.y);
        const float y2 = siluf_(acc[nt][2] * s4.z + b4.z);
        const float y3 = siluf_(acc[nt][3] * s4.w + b4.w);
        *reinterpret_cast<uint2*>(op + ob) =
            make_uint2(f2bf(y0) | ((unsigned)f2bf(y1) << 16),
                       f2bf(y2) | ((unsigned)f2bf(y3) << 16));
    }
}

// ---------------------------------------------------------------------------
// k2 (r14 version): 3x3 conv (128->27) + bias via MFMA. XCD-affine blocks.
// ---------------------------------------------------------------------------
__global__ __launch_bounds__(256) void k2_off(
    const ushort_t* __restrict__ xm_bf, const ushort_t* __restrict__ WoB,
    const float* __restrict__ obias, float* __restrict__ om)
{
    __shared__ __align__(16) ushort_t A[2][64 * 128];   // 2 x 16 KB
    __shared__ __align__(16) float T[32 * 64];          // 8 KB

    const int t = threadIdx.x;
    const int lane = t & 63;
    const int wave = t >> 6;
    const int p0 = xcd_bid800(blockIdx.x) * 64;
    const int bb = p0 / HW;
    const int hw0 = p0 % HW;

    const int spx = t & 63;
    const int hws = hw0 + spx;
    const int hh = hws / WW, wwp = hws % WW;

    auto STAGE = [&](int q, int buf) {
        const int dy = q / 3 - 1, dx = q % 3 - 1;
        const int y = hh + dy, xx = wwp + dx;
        const bool valid = ((unsigned)y < 80u) && ((unsigned)xx < 80u);
        const ushort_t* src = xm_bf + ((size_t)bb * HW + y * WW + xx) * 128 + wave * 32;
#pragma unroll
        for (int s = 0; s < 4; ++s) {
            uint4 v = make_uint4(0u, 0u, 0u, 0u);
            if (valid) v = *reinterpret_cast<const uint4*>(src + s * 8);
            const int cslot = wave * 4 + s;
            *reinterpret_cast<uint4*>(&A[buf][spx * 128 + ((cslot ^ (spx & 7)) << 3)]) = v;
        }
    };

    const int q4 = lane >> 4, ln = lane & 15;
    f32x4 acc[2] = {};

    auto GEMM = [&](int q, int buf) {
#pragma unroll
        for (int ks = 0; ks < 4; ++ks) {
            const int px = wave * 16 + ln;
            const int elem = px * 128 + (((ks * 4 + q4) ^ (px & 7)) << 3);
            const short8 a = *reinterpret_cast<const short8*>(&A[buf][elem]);
#pragma unroll
            for (int nf = 0; nf < 2; ++nf) {
                const int chunk = nf * 36 + q * 4 + ks;
                const short8 b = *reinterpret_cast<const short8*>(WoB + chunk * 512 + lane * 8);
                acc[nf] = __builtin_amdgcn_mfma_f32_16x16x32_bf16(a, b, acc[nf], 0, 0, 0);
            }
        }
    };

    STAGE(0, 0);
    __syncthreads();
    for (int q = 0; q < 9; ++q) {
        if (q < 8) STAGE(q + 1, (q + 1) & 1);
        GEMM(q, q & 1);
        __syncthreads();
    }

#pragma unroll
    for (int nf = 0; nf < 2; ++nf)
#pragma unroll
        for (int r = 0; r < 4; ++r) {
            const int o = nf * 16 + ln;
            const int px = wave * 16 + q4 * 4 + r;
            T[o * 64 + px] = acc[nf][r];
        }
    __syncthreads();
    for (int i = t; i < 27 * 64; i += 256) {
        const int o = i >> 6, px = i & 63;
        om[((size_t)bb * 27 + o) * HW + hw0 + px] = T[i] + obias[o];
    }
}

// ---------------------------------------------------------------------------
// k3 v10: BARRIER-FREE register-resident DCN (k1-style). 256 thr = 4 waves,
// wave = 32 px x 128 o (2M x 2N grid). Each lane builds its own A-fragments
// from global (4 corner uint4 loads per px per ks), blends in-register, feeds
// MFMA directly. No S tile, no per-tap barriers; geo in LDS (1 barrier).
// A-gather is 2x redundant (wN pair) but L1/L2-served; B traffic unchanged.
// ---------------------------------------------------------------------------
__global__ __launch_bounds__(256, 4) void k3_dcn(
    const ushort_t* __restrict__ xm_bf, const float* __restrict__ om,
    const ushort_t* __restrict__ WdB,
    const float* __restrict__ g, const float* __restrict__ be,
    const float* __restrict__ mu, const float* __restrict__ va,
    float* __restrict__ out)
{
    __shared__ __align__(16) float4 geoW[9][64];       // 9 KB
    __shared__ __align__(16) int4   geoI[9][64];       // 9 KB

    const int t    = threadIdx.x;
    const int lane = t & 63;
    const int wv   = t >> 6;                 // 0..3
    const int wM   = wv >> 1, wN = wv & 1;
    const int p0   = xcd_bid800(blockIdx.x) * 64;
    const int bb   = p0 / HW;
    const int hw0  = p0 % HW;

    // ---- geometry for all 9 taps (once) ----
    for (int it = t; it < 576; it += 256) {
        const int tap = it >> 6, px = it & 63;
        const int hw = hw0 + px;
        const int h = hw / WW, w = hw % WW;
        const float* ob = om + (size_t)bb * 27 * HW + hw;
        const float oy = ob[(2 * tap) * HW];
        const float ox = ob[(2 * tap + 1) * HW];
        const float mk = sigmoidf_(ob[(18 + tap) * HW]);
        float py  = (float)(h - 1 + tap / 3) + oy;
        float pxf = (float)(w - 1 + tap % 3) + ox;
        py  = fminf(fmaxf(py, -1000.f), 1000.f);
        pxf = fminf(fmaxf(pxf, -1000.f), 1000.f);
        const float fy = floorf(py), fx = floorf(pxf);
        const int y0 = (int)fy, x0 = (int)fx, y1 = y0 + 1, x1 = x0 + 1;
        const float wy = py - fy, wx = pxf - fx;
        const float vy0 = ((unsigned)y0 < 80u) ? 1.f : 0.f;
        const float vy1 = ((unsigned)y1 < 80u) ? 1.f : 0.f;
        const float vx0 = ((unsigned)x0 < 80u) ? 1.f : 0.f;
        const float vx1 = ((unsigned)x1 < 80u) ? 1.f : 0.f;
        float4 wvv;
        wvv.x = (1.f - wy) * (1.f - wx) * vy0 * vx0 * mk;
        wvv.y = (1.f - wy) * wx * vy0 * vx1 * mk;
        wvv.z = wy * (1.f - wx) * vy1 * vx0 * mk;
        wvv.w = wy * wx * vy1 * vx1 * mk;
        const int cy0 = min(max(y0, 0), 79), cy1 = min(max(y1, 0), 79);
        const int cx0 = min(max(x0, 0), 79), cx1 = min(max(x1, 0), 79);
        int4 iv;
        iv.x = cy0 * WW + cx0; iv.y = cy0 * WW + cx1;
        iv.z = cy1 * WW + cx0; iv.w = cy1 * WW + cx1;
        geoW[tap][px] = wvv;
        geoI[tap][px] = iv;
    }
    __syncthreads();

    const ushort_t* xb = xm_bf + (size_t)bb * HW * 128;
    const int q = lane >> 4, ln = lane & 15;
    const int pxl0 = wM * 32 + ln;        // local px, M-tile 0
    const int pxl1 = pxl0 + 16;           // local px, M-tile 1

    f32x4 acc[2][8] = {};

    for (int tap = 0; tap < 9; ++tap) {
        const int4  iv0 = geoI[tap][pxl0];
        const int4  iv1 = geoI[tap][pxl1];
        const float4 wv0 = geoW[tap][pxl0];
        const float4 wv1 = geoW[tap][pxl1];
#pragma unroll
        for (int ks = 0; ks < 4; ++ks) {
            const int co = (ks * 4 + q) * 8;   // 8-channel chunk for this lane
            const uint4 c00 = *reinterpret_cast<const uint4*>(xb + (size_t)iv0.x * 128 + co);
            const uint4 c01 = *reinterpret_cast<const uint4*>(xb + (size_t)iv0.y * 128 + co);
            const uint4 c10 = *reinterpret_cast<const uint4*>(xb + (size_t)iv0.z * 128 + co);
            const uint4 c11 = *reinterpret_cast<const uint4*>(xb + (size_t)iv0.w * 128 + co);
            const uint4 d00 = *reinterpret_cast<const uint4*>(xb + (size_t)iv1.x * 128 + co);
            const uint4 d01 = *reinterpret_cast<const uint4*>(xb + (size_t)iv1.y * 128 + co);
            const uint4 d10 = *reinterpret_cast<const uint4*>(xb + (size_t)iv1.z * 128 + co);
            const uint4 d11 = *reinterpret_cast<const uint4*>(xb + (size_t)iv1.w * 128 + co);
            const short8 a0 = blend8(wv0, c00, c01, c10, c11);
            const short8 a1 = blend8(wv1, d00, d01, d10, d11);
#pragma unroll
            for (int nt = 0; nt < 8; ++nt) {
                const int ot = wN * 8 + nt;
                const int chunk = ot * 36 + tap * 4 + ks;
                const short8 b = *reinterpret_cast<const short8*>(WdB + chunk * 512 + lane * 8);
                acc[0][nt] = __builtin_amdgcn_mfma_f32_16x16x32_bf16(a0, b, acc[0][nt], 0, 0, 0);
                acc[1][nt] = __builtin_amdgcn_mfma_f32_16x16x32_bf16(a1, b, acc[1][nt], 0, 0, 0);
            }
        }
    }

    // ---- epilogue: BN + SiLU, store ----
#pragma unroll
    for (int nt = 0; nt < 8; ++nt) {
        const int o = wN * 128 + nt * 16 + ln;
        const float sc = g[o] * rsqrtf(va[o] + 1e-5f);
        const float sh = be[o] - mu[o] * sc;
        float* obase = out + (size_t)bb * 256 * HW + (size_t)o * HW;
#pragma unroll
        for (int mt = 0; mt < 2; ++mt) {
            float4 st;
            st.x = siluf_(acc[mt][nt][0] * sc + sh);
            st.y = siluf_(acc[mt][nt][1] * sc + sh);
            st.z = siluf_(acc[mt][nt][2] * sc + sh);
            st.w = siluf_(acc[mt][nt][3] * sc + sh);
            *reinterpret_cast<float4*>(obase + hw0 + wM * 32 + mt * 16 + q * 4) = st;
        }
    }
}

// ---------------------------------------------------------------------------
extern "C" void kernel_launch(void* const* d_in, const int* in_sizes, int n_in,
                              void* d_out, int out_size, void* d_ws, size_t ws_size,
                              hipStream_t stream)
{
    const float* x        = (const float*)d_in[0];
    const float* reduce_w = (const float*)d_in[1];
    const float* rg       = (const float*)d_in[2];
    const float* rb       = (const float*)d_in[3];
    const float* rm       = (const float*)d_in[4];
    const float* rv       = (const float*)d_in[5];
    const float* off_w    = (const float*)d_in[6];
    const float* off_b    = (const float*)d_in[7];
    const float* dcn_w    = (const float*)d_in[8];
    const float* dg       = (const float*)d_in[9];
    const float* db       = (const float*)d_in[10];
    const float* dm       = (const float*)d_in[11];
    const float* dv       = (const float*)d_in[12];

    float* ws  = (float*)d_ws;
    ushort_t* xm_bf = (ushort_t*)ws;                 // 6,553,600 bf16
    float* om   = ws + 3276800;                      // 1,382,400 f
    ushort_t* WB   = (ushort_t*)(om + 1382400);      // 65,536 bf16
    ushort_t* WoB  = WB + 65536;                     // 36,864 bf16
    ushort_t* WdB  = WoB + 36864;                    // 294,912 bf16
    float* scr = (float*)(WdB + 294912);             // 128 f
    float* shr = scr + 128;                          // 128 f

    k0_prep<<<dim3(1552), dim3(256), 0, stream>>>(reduce_w, off_w, dcn_w,
                                                  rg, rb, rm, rv,
                                                  WB, WoB, WdB, scr, shr);
    k1_reduce<<<dim3(800), dim3(256), 0, stream>>>(x, WB, scr, shr, xm_bf);
    k2_off<<<dim3(800), dim3(256), 0, stream>>>(xm_bf, WoB, off_b, om);
    k3_dcn<<<dim3(800), dim3(256), 0, stream>>>(xm_bf, om, WdB, dg, db, dm, dv, (float*)d_out);
}

// Round 17
// 166.966 us; speedup vs baseline: 3.1408x; 3.1408x over previous
//
#include <hip/hip_runtime.h>

constexpr int HW  = 6400;   // 80*80
constexpr int WW  = 80;

typedef __attribute__((ext_vector_type(8))) short short8;   // 8 bf16 = 4 VGPR
typedef __attribute__((ext_vector_type(4))) float f32x4;
typedef unsigned short ushort_t;

__device__ __forceinline__ float sigmoidf_(float x) { return 1.f / (1.f + __expf(-x)); }
__device__ __forceinline__ float siluf_(float y) { return y / (1.f + __expf(-y)); }
__device__ __forceinline__ ushort_t f2bf(float f) {   // RNE f32->bf16
    unsigned u = __float_as_uint(f);
    u += 0x7FFFu + ((u >> 16) & 1u);
    return (ushort_t)(u >> 16);
}
__device__ __forceinline__ float bf2f(ushort_t h) {
    return __uint_as_float(((unsigned)h) << 16);
}
// XCD-affinity swizzle for 800-block grids (800 = 8 XCDs x 100): block
// blockIdx.x lands on XCD (blockIdx.x % 8) [empirical round-robin]; remap so
// XCD k owns contiguous bid range [k*100,(k+1)*100) = batch image k exactly.
// Verified r14: k3 FETCH_SIZE 40 MB -> 13.6 MB (= exactly one xm read).
__device__ __forceinline__ int xcd_bid800(int b) { return (b & 7) * 100 + (b >> 3); }

// ---------------------------------------------------------------------------
// k0: weight prep (bf16 MFMA fragment layouts)
//  WB:  reduce_w frags. chunk = nt*16+kks (nt 0..7, kks 0..15);
//       entry lane*8+e: o = nt*16+(lane&15), kk = kks*32+(lane>>4)*8+e (kk = cs)
//  WoB: off_w frags, chunk = nf*36+ksg (nf 0..1), K = q*128+c
//  WdB: dcn_w frags, chunk = ot*36+ksg (ot 0..15), K = tap*128+c
//  scr/shr: reduce-BN scale/shift fp32
// ---------------------------------------------------------------------------
__global__ __launch_bounds__(256) void k0_prep(
    const float* __restrict__ rw, const float* __restrict__ ow,
    const float* __restrict__ dw,
    const float* __restrict__ rg, const float* __restrict__ rb,
    const float* __restrict__ rm, const float* __restrict__ rv,
    ushort_t* __restrict__ WB,
    ushort_t* __restrict__ WoB, ushort_t* __restrict__ WdB,
    float* __restrict__ scr, float* __restrict__ shr)
{
    const int i = blockIdx.x * 256 + threadIdx.x;
    if (blockIdx.x == 0 && threadIdx.x < 128) {
        const int m = threadIdx.x;
        const float sc = rg[m] * rsqrtf(rv[m] + 1e-5f);
        scr[m] = sc;
        shr[m] = rb[m] - rm[m] * sc;
    }
    if (i < 65536) {                       // WB: 128 chunks * 512
        const int e = i & 7;
        const int lane = (i >> 3) & 63;
        const int chunkW = i >> 9;         // 0..127
        const int nt = chunkW >> 4, kks = chunkW & 15;
        const int kk = kks * 32 + ((lane >> 4) << 3) + e;   // cs 0..511
        const int o = (nt << 4) + (lane & 15);              // out ch 0..127
        WB[i] = f2bf(rw[o * 512 + kk]);
    }
    const int j = i - 65536;
    if (j >= 0 && j < 36864) {             // WoB: 2*36*512
        const int e = j & 7;
        const int lane = (j >> 3) & 63;
        const int chunk = j >> 9;
        const int nf = chunk / 36, ksg = chunk % 36;
        const int kk = ksg * 32 + ((lane >> 4) << 3) + e;
        const int q = kk >> 7, c = kk & 127;
        const int o = (nf << 4) + (lane & 15);
        WoB[j] = (o < 27) ? f2bf(ow[o * 1152 + c * 9 + q]) : (ushort_t)0;
    }
    const int l = j - 36864;
    if (l >= 0 && l < 294912) {            // WdB: 16*36*512
        const int e = l & 7;
        const int lane = (l >> 3) & 63;
        const int chunk = l >> 9;
        const int ot = chunk / 36, ksg = chunk % 36;
        const int kk = ksg * 32 + ((lane >> 4) << 3) + e;
        const int tap = kk >> 7, c = kk & 127;
        const int o = (ot << 4) + (lane & 15);
        WdB[l] = f2bf(dw[o * 1152 + c * 9 + tap]);
    }
}

// ---------------------------------------------------------------------------
// k1 v3: space-to-depth + 1x1 conv as bf16 MFMA, NO LDS. XCD-affine blocks.
// ---------------------------------------------------------------------------
__global__ __launch_bounds__(256) void k1_reduce(
    const float* __restrict__ x,
    const ushort_t* __restrict__ WB,
    const float* __restrict__ scr, const float* __restrict__ shr,
    ushort_t* __restrict__ xm_bf)
{
    const int t    = threadIdx.x;
    const int lane = t & 63;
    const int wave = t >> 6;
    const int q = lane >> 4, ln = lane & 15;
    const int p0 = xcd_bid800(blockIdx.x) * 64;
    const int bb = p0 / HW;
    const int px = wave * 16 + ln;
    const int hw = (p0 % HW) + px;
    const int h = hw / WW, w = hw % WW;
    const float* xb = x + (size_t)bb * 128 * 25600 + (2 * h) * 160 + 2 * w;

    f32x4 acc[8] = {};

#pragma unroll 4
    for (int kks = 0; kks < 16; ++kks) {
        const int c0 = kks * 8 + q * 2;       // 2 channels per fragment
        const float* pc0 = xb + (size_t)c0 * 25600;
        const float* pc1 = pc0 + 25600;
        const float2 a0 = *reinterpret_cast<const float2*>(pc0);
        const float2 a1 = *reinterpret_cast<const float2*>(pc0 + 160);
        const float2 b0 = *reinterpret_cast<const float2*>(pc1);
        const float2 b1 = *reinterpret_cast<const float2*>(pc1 + 160);
        short8 p;
        p[0] = (short)f2bf(a0.x); p[1] = (short)f2bf(a0.y);
        p[2] = (short)f2bf(a1.x); p[3] = (short)f2bf(a1.y);
        p[4] = (short)f2bf(b0.x); p[5] = (short)f2bf(b0.y);
        p[6] = (short)f2bf(b1.x); p[7] = (short)f2bf(b1.y);
#pragma unroll
        for (int nt = 0; nt < 8; ++nt) {
            const short8 wf = *reinterpret_cast<const short8*>(WB + ((nt << 4) + kks) * 512 + lane * 8);
            acc[nt] = __builtin_amdgcn_mfma_f32_16x16x32_bf16(wf, p, acc[nt], 0, 0, 0);
        }
    }

    const int pi = p0 + px;
    ushort_t* op = xm_bf + (size_t)pi * 128;
#pragma unroll
    for (int nt = 0; nt < 8; ++nt) {
        const int ob = nt * 16 + q * 4;
        const float4 s4 = *reinterpret_cast<const float4*>(scr + ob);
        const float4 b4 = *reinterpret_cast<const float4*>(shr + ob);
        const float y0 = siluf_(acc[nt][0] * s4.x + b4.x);
        const float y1 = siluf_(acc[nt][1] * s4.y + b4.y);
        const float y2 = siluf_(acc[nt][2] * s4.z + b4.z);
        const float y3 = siluf_(acc[nt][3] * s4.w + b4.w);
        *reinterpret_cast<uint2*>(op + ob) =
            make_uint2(f2bf(y0) | ((unsigned)f2bf(y1) << 16),
                       f2bf(y2) | ((unsigned)f2bf(y3) << 16));
    }
}

// ---------------------------------------------------------------------------
// k2: 3x3 conv (128->27) + bias via MFMA. M=64px/block, K=1152, N=32.
// XCD-affine blocks.
// ---------------------------------------------------------------------------
__global__ __launch_bounds__(256) void k2_off(
    const ushort_t* __restrict__ xm_bf, const ushort_t* __restrict__ WoB,
    const float* __restrict__ obias, float* __restrict__ om)
{
    __shared__ __align__(16) ushort_t A[2][64 * 128];   // 2 x 16 KB
    __shared__ __align__(16) float T[32 * 64];          // 8 KB

    const int t = threadIdx.x;
    const int lane = t & 63;
    const int wave = t >> 6;
    const int p0 = xcd_bid800(blockIdx.x) * 64;
    const int bb = p0 / HW;
    const int hw0 = p0 % HW;

    const int spx = t & 63;
    const int hws = hw0 + spx;
    const int hh = hws / WW, wwp = hws % WW;

    auto STAGE = [&](int q, int buf) {
        const int dy = q / 3 - 1, dx = q % 3 - 1;
        const int y = hh + dy, xx = wwp + dx;
        const bool valid = ((unsigned)y < 80u) && ((unsigned)xx < 80u);
        const ushort_t* src = xm_bf + ((size_t)bb * HW + y * WW + xx) * 128 + wave * 32;
#pragma unroll
        for (int s = 0; s < 4; ++s) {
            uint4 v = make_uint4(0u, 0u, 0u, 0u);
            if (valid) v = *reinterpret_cast<const uint4*>(src + s * 8);
            const int cslot = wave * 4 + s;
            *reinterpret_cast<uint4*>(&A[buf][spx * 128 + ((cslot ^ (spx & 7)) << 3)]) = v;
        }
    };

    const int q4 = lane >> 4, ln = lane & 15;
    f32x4 acc[2] = {};

    auto GEMM = [&](int q, int buf) {
#pragma unroll
        for (int ks = 0; ks < 4; ++ks) {
            const int px = wave * 16 + ln;
            const int elem = px * 128 + (((ks * 4 + q4) ^ (px & 7)) << 3);
            const short8 a = *reinterpret_cast<const short8*>(&A[buf][elem]);
#pragma unroll
            for (int nf = 0; nf < 2; ++nf) {
                const int chunk = nf * 36 + q * 4 + ks;
                const short8 b = *reinterpret_cast<const short8*>(WoB + chunk * 512 + lane * 8);
                acc[nf] = __builtin_amdgcn_mfma_f32_16x16x32_bf16(a, b, acc[nf], 0, 0, 0);
            }
        }
    };

    STAGE(0, 0);
    __syncthreads();
    for (int q = 0; q < 9; ++q) {
        if (q < 8) STAGE(q + 1, (q + 1) & 1);
        GEMM(q, q & 1);
        __syncthreads();
    }

#pragma unroll
    for (int nf = 0; nf < 2; ++nf)
#pragma unroll
        for (int r = 0; r < 4; ++r) {
            const int o = nf * 16 + ln;
            const int px = wave * 16 + q4 * 4 + r;
            T[o * 64 + px] = acc[nf][r];
        }
    __syncthreads();
    for (int i = t; i < 27 * 64; i += 256) {
        const int o = i >> 6, px = i & 63;
        om[((size_t)bb * 27 + o) * HW + hw0 + px] = T[i] + obias[o];
    }
}

// ---------------------------------------------------------------------------
// k3 v9 (r14 verbatim): T14 async split, fat geo LDS, pr[8], XCD-affine.
// 512 thr (8 waves), 64 px x 256 o per block.
// ---------------------------------------------------------------------------
__global__ __launch_bounds__(512) void k3_dcn(
    const ushort_t* __restrict__ xm_bf, const float* __restrict__ om,
    const ushort_t* __restrict__ WdB,
    const float* __restrict__ g, const float* __restrict__ be,
    const float* __restrict__ mu, const float* __restrict__ va,
    float* __restrict__ out)
{
    __shared__ __align__(16) ushort_t S[2][64 * 128];  // 2 x 16 KB
    __shared__ __align__(16) float4 geoW[9][64];       // 9 KB
    __shared__ __align__(16) int4   geoI[9][64];       // 9 KB

    const int t    = threadIdx.x;
    const int lane = t & 63;
    const int wave = t >> 6;
    const int p0   = xcd_bid800(blockIdx.x) * 64;
    const int bb   = p0 / HW;
    const int hw0  = p0 % HW;

    for (int it = t; it < 576; it += 512) {
        const int tap = it >> 6, px = it & 63;
        const int hw = hw0 + px;
        const int h = hw / WW, w = hw % WW;
        const float* ob = om + (size_t)bb * 27 * HW + hw;
        const float oy = ob[(2 * tap) * HW];
        const float ox = ob[(2 * tap + 1) * HW];
        const float mk = sigmoidf_(ob[(18 + tap) * HW]);
        float py  = (float)(h - 1 + tap / 3) + oy;
        float pxf = (float)(w - 1 + tap % 3) + ox;
        py  = fminf(fmaxf(py, -1000.f), 1000.f);
        pxf = fminf(fmaxf(pxf, -1000.f), 1000.f);
        const float fy = floorf(py), fx = floorf(pxf);
        const int y0 = (int)fy, x0 = (int)fx, y1 = y0 + 1, x1 = x0 + 1;
        const float wy = py - fy, wx = pxf - fx;
        const float vy0 = ((unsigned)y0 < 80u) ? 1.f : 0.f;
        const float vy1 = ((unsigned)y1 < 80u) ? 1.f : 0.f;
        const float vx0 = ((unsigned)x0 < 80u) ? 1.f : 0.f;
        const float vx1 = ((unsigned)x1 < 80u) ? 1.f : 0.f;
        float4 wv;
        wv.x = (1.f - wy) * (1.f - wx) * vy0 * vx0 * mk;
        wv.y = (1.f - wy) * wx * vy0 * vx1 * mk;
        wv.z = wy * (1.f - wx) * vy1 * vx0 * mk;
        wv.w = wy * wx * vy1 * vx1 * mk;
        const int cy0 = min(max(y0, 0), 79), cy1 = min(max(y1, 0), 79);
        const int cx0 = min(max(x0, 0), 79), cx1 = min(max(x1, 0), 79);
        int4 iv;
        iv.x = cy0 * WW + cx0; iv.y = cy0 * WW + cx1;
        iv.z = cy1 * WW + cx0; iv.w = cy1 * WW + cx1;
        geoW[tap][px] = wv;
        geoI[tap][px] = iv;
    }
    __syncthreads();

    const ushort_t* xb = xm_bf + (size_t)bb * HW * 128;

    const int spx = t >> 3;
    const int scg = t & 7;

    // prefetched corner data: [corner 0..3][half 0..1]
    uint4 pr[8];

    auto ISSUE = [&](int tap) {
        const int4 iv = geoI[tap][spx];
        const uint4* c00 = reinterpret_cast<const uint4*>(xb + (size_t)iv.x * 128 + scg * 16);
        const uint4* c01 = reinterpret_cast<const uint4*>(xb + (size_t)iv.y * 128 + scg * 16);
        const uint4* c10 = reinterpret_cast<const uint4*>(xb + (size_t)iv.z * 128 + scg * 16);
        const uint4* c11 = reinterpret_cast<const uint4*>(xb + (size_t)iv.w * 128 + scg * 16);
        pr[0] = c00[0]; pr[1] = c00[1];
        pr[2] = c01[0]; pr[3] = c01[1];
        pr[4] = c10[0]; pr[5] = c10[1];
        pr[6] = c11[0]; pr[7] = c11[1];
    };

    auto BLEND_WRITE = [&](int tap, int bufIdx) {
        const float4 wv = geoW[tap][spx];
#pragma unroll
        for (int half = 0; half < 2; ++half) {
            const unsigned* ap = (const unsigned*)&pr[0 + half];
            const unsigned* bp = (const unsigned*)&pr[2 + half];
            const unsigned* cp = (const unsigned*)&pr[4 + half];
            const unsigned* dp = (const unsigned*)&pr[6 + half];
            unsigned pk[4];
#pragma unroll
            for (int u = 0; u < 4; ++u) {
                const float alo = __uint_as_float(ap[u] << 16), ahi = __uint_as_float(ap[u] & 0xFFFF0000u);
                const float blo = __uint_as_float(bp[u] << 16), bhi = __uint_as_float(bp[u] & 0xFFFF0000u);
                const float clo = __uint_as_float(cp[u] << 16), chi = __uint_as_float(cp[u] & 0xFFFF0000u);
                const float dlo = __uint_as_float(dp[u] << 16), dhi = __uint_as_float(dp[u] & 0xFFFF0000u);
                const float slo = wv.x * alo + wv.y * blo + wv.z * clo + wv.w * dlo;
                const float shi = wv.x * ahi + wv.y * bhi + wv.z * chi + wv.w * dhi;
                pk[u] = (unsigned)f2bf(slo) | ((unsigned)f2bf(shi) << 16);
            }
            const int cslot = scg * 2 + half;
            const int elem  = spx * 128 + ((cslot ^ (spx & 7)) << 3);
            *reinterpret_cast<uint4*>(&S[bufIdx][elem]) =
                make_uint4(pk[0], pk[1], pk[2], pk[3]);
        }
    };

    const int wM = wave >> 2, wN = wave & 3;
    const int q = lane >> 4, ln = lane & 15;
    f32x4 acc[2][4] = {};

    auto GEMM = [&](int tap, int bufIdx) {
#pragma unroll
        for (int ks = 0; ks < 4; ++ks) {
            short8 a0, a1;
            {
                const int px = wM * 32 + ln;
                const int elem = px * 128 + (((ks * 4 + q) ^ (px & 7)) << 3);
                a0 = *reinterpret_cast<const short8*>(&S[bufIdx][elem]);
            }
            {
                const int px = wM * 32 + 16 + ln;
                const int elem = px * 128 + (((ks * 4 + q) ^ (px & 7)) << 3);
                a1 = *reinterpret_cast<const short8*>(&S[bufIdx][elem]);
            }
#pragma unroll
            for (int nt = 0; nt < 4; ++nt) {
                const int ot = wN * 4 + nt;
                const int chunk = ot * 36 + tap * 4 + ks;
                const short8 b = *reinterpret_cast<const short8*>(WdB + chunk * 512 + lane * 8);
                acc[0][nt] = __builtin_amdgcn_mfma_f32_16x16x32_bf16(a0, b, acc[0][nt], 0, 0, 0);
                acc[1][nt] = __builtin_amdgcn_mfma_f32_16x16x32_bf16(a1, b, acc[1][nt], 0, 0, 0);
            }
        }
    };

    // prologue: fill buf0 for tap 0
    ISSUE(0);
    BLEND_WRITE(0, 0);
    __syncthreads();

    for (int tap = 0; tap < 9; ++tap) {
        if (tap < 8) ISSUE(tap + 1);           // loads in flight across GEMM
        GEMM(tap, tap & 1);
        if (tap < 8) BLEND_WRITE(tap + 1, (tap + 1) & 1);
        __syncthreads();
    }

    float sc[4], sh[4];
#pragma unroll
    for (int nt = 0; nt < 4; ++nt) {
        const int o = wN * 64 + nt * 16 + ln;
        sc[nt] = g[o] * rsqrtf(va[o] + 1e-5f);
        sh[nt] = be[o] - mu[o] * sc[nt];
    }
#pragma unroll
    for (int mt = 0; mt < 2; ++mt)
#pragma unroll
        for (int nt = 0; nt < 4; ++nt) {
            const int o = wN * 64 + nt * 16 + ln;
            float* obase = out + (size_t)bb * 256 * HW + (size_t)o * HW;
            float4 st;
            st.x = siluf_(acc[mt][nt][0] * sc[nt] + sh[nt]);
            st.y = siluf_(acc[mt][nt][1] * sc[nt] + sh[nt]);
            st.z = siluf_(acc[mt][nt][2] * sc[nt] + sh[nt]);
            st.w = siluf_(acc[mt][nt][3] * sc[nt] + sh[nt]);
            *reinterpret_cast<float4*>(obase + hw0 + wM * 32 + mt * 16 + q * 4) = st;
        }
}

// ---------------------------------------------------------------------------
extern "C" void kernel_launch(void* const* d_in, const int* in_sizes, int n_in,
                              void* d_out, int out_size, void* d_ws, size_t ws_size,
                              hipStream_t stream)
{
    const float* x        = (const float*)d_in[0];
    const float* reduce_w = (const float*)d_in[1];
    const float* rg       = (const float*)d_in[2];
    const float* rb       = (const float*)d_in[3];
    const float* rm       = (const float*)d_in[4];
    const float* rv       = (const float*)d_in[5];
    const float* off_w    = (const float*)d_in[6];
    const float* off_b    = (const float*)d_in[7];
    const float* dcn_w    = (const float*)d_in[8];
    const float* dg       = (const float*)d_in[9];
    const float* db       = (const float*)d_in[10];
    const float* dm       = (const float*)d_in[11];
    const float* dv       = (const float*)d_in[12];

    float* ws  = (float*)d_ws;
    ushort_t* xm_bf = (ushort_t*)ws;                 // 6,553,600 bf16
    float* om   = ws + 3276800;                      // 1,382,400 f
    ushort_t* WB   = (ushort_t*)(om + 1382400);      // 65,536 bf16
    ushort_t* WoB  = WB + 65536;                     // 36,864 bf16
    ushort_t* WdB  = WoB + 36864;                    // 294,912 bf16
    float* scr = (float*)(WdB + 294912);             // 128 f
    float* shr = scr + 128;                          // 128 f

    k0_prep<<<dim3(1552), dim3(256), 0, stream>>>(reduce_w, off_w, dcn_w,
                                                  rg, rb, rm, rv,
                                                  WB, WoB, WdB, scr, shr);
    k1_reduce<<<dim3(800), dim3(256), 0, stream>>>(x, WB, scr, shr, xm_bf);
    k2_off<<<dim3(800), dim3(256), 0, stream>>>(xm_bf, WoB, off_b, om);
    k3_dcn<<<dim3(800), dim3(512), 0, stream>>>(xm_bf, om, WdB, dg, db, dm, dv, (float*)d_out);
}

// Round 18
// 158.485 us; speedup vs baseline: 3.3088x; 1.0535x over previous
//
#include <hip/hip_runtime.h>

constexpr int HW  = 6400;   // 80*80
constexpr int WW  = 80;

typedef __attribute__((ext_vector_type(8))) short short8;   // 8 bf16 = 4 VGPR
typedef __attribute__((ext_vector_type(4))) float f32x4;
typedef unsigned short ushort_t;

__device__ __forceinline__ float sigmoidf_(float x) { return 1.f / (1.f + __expf(-x)); }
__device__ __forceinline__ float siluf_(float y) { return y / (1.f + __expf(-y)); }
__device__ __forceinline__ ushort_t f2bf(float f) {   // RNE f32->bf16
    unsigned u = __float_as_uint(f);
    u += 0x7FFFu + ((u >> 16) & 1u);
    return (ushort_t)(u >> 16);
}
__device__ __forceinline__ float bf2f(ushort_t h) {
    return __uint_as_float(((unsigned)h) << 16);
}
// XCD-affinity swizzle for 800-block grids (800 = 8 XCDs x 100).
// Verified r14: k3 FETCH_SIZE 40 MB -> 13.6 MB (= exactly one xm read).
__device__ __forceinline__ int xcd_bid800(int b) { return (b & 7) * 100 + (b >> 3); }

// ---------------------------------------------------------------------------
// k0: weight prep (bf16 MFMA fragment layouts)
// ---------------------------------------------------------------------------
__global__ __launch_bounds__(256) void k0_prep(
    const float* __restrict__ rw, const float* __restrict__ ow,
    const float* __restrict__ dw,
    const float* __restrict__ rg, const float* __restrict__ rb,
    const float* __restrict__ rm, const float* __restrict__ rv,
    ushort_t* __restrict__ WB,
    ushort_t* __restrict__ WoB, ushort_t* __restrict__ WdB,
    float* __restrict__ scr, float* __restrict__ shr)
{
    const int i = blockIdx.x * 256 + threadIdx.x;
    if (blockIdx.x == 0 && threadIdx.x < 128) {
        const int m = threadIdx.x;
        const float sc = rg[m] * rsqrtf(rv[m] + 1e-5f);
        scr[m] = sc;
        shr[m] = rb[m] - rm[m] * sc;
    }
    if (i < 65536) {                       // WB: 128 chunks * 512
        const int e = i & 7;
        const int lane = (i >> 3) & 63;
        const int chunkW = i >> 9;         // 0..127
        const int nt = chunkW >> 4, kks = chunkW & 15;
        const int kk = kks * 32 + ((lane >> 4) << 3) + e;   // cs 0..511
        const int o = (nt << 4) + (lane & 15);              // out ch 0..127
        WB[i] = f2bf(rw[o * 512 + kk]);
    }
    const int j = i - 65536;
    if (j >= 0 && j < 36864) {             // WoB: 2*36*512
        const int e = j & 7;
        const int lane = (j >> 3) & 63;
        const int chunk = j >> 9;
        const int nf = chunk / 36, ksg = chunk % 36;
        const int kk = ksg * 32 + ((lane >> 4) << 3) + e;
        const int q = kk >> 7, c = kk & 127;
        const int o = (nf << 4) + (lane & 15);
        WoB[j] = (o < 27) ? f2bf(ow[o * 1152 + c * 9 + q]) : (ushort_t)0;
    }
    const int l = j - 36864;
    if (l >= 0 && l < 294912) {            // WdB: 16*36*512
        const int e = l & 7;
        const int lane = (l >> 3) & 63;
        const int chunk = l >> 9;
        const int ot = chunk / 36, ksg = chunk % 36;
        const int kk = ksg * 32 + ((lane >> 4) << 3) + e;
        const int tap = kk >> 7, c = kk & 127;
        const int o = (ot << 4) + (lane & 15);
        WdB[l] = f2bf(dw[o * 1152 + c * 9 + tap]);
    }
}

// ---------------------------------------------------------------------------
// k1 v3: space-to-depth + 1x1 conv as bf16 MFMA, NO LDS. XCD-affine blocks.
// ---------------------------------------------------------------------------
__global__ __launch_bounds__(256) void k1_reduce(
    const float* __restrict__ x,
    const ushort_t* __restrict__ WB,
    const float* __restrict__ scr, const float* __restrict__ shr,
    ushort_t* __restrict__ xm_bf)
{
    const int t    = threadIdx.x;
    const int lane = t & 63;
    const int wave = t >> 6;
    const int q = lane >> 4, ln = lane & 15;
    const int p0 = xcd_bid800(blockIdx.x) * 64;
    const int bb = p0 / HW;
    const int px = wave * 16 + ln;
    const int hw = (p0 % HW) + px;
    const int h = hw / WW, w = hw % WW;
    const float* xb = x + (size_t)bb * 128 * 25600 + (2 * h) * 160 + 2 * w;

    f32x4 acc[8] = {};

#pragma unroll 4
    for (int kks = 0; kks < 16; ++kks) {
        const int c0 = kks * 8 + q * 2;       // 2 channels per fragment
        const float* pc0 = xb + (size_t)c0 * 25600;
        const float* pc1 = pc0 + 25600;
        const float2 a0 = *reinterpret_cast<const float2*>(pc0);
        const float2 a1 = *reinterpret_cast<const float2*>(pc0 + 160);
        const float2 b0 = *reinterpret_cast<const float2*>(pc1);
        const float2 b1 = *reinterpret_cast<const float2*>(pc1 + 160);
        short8 p;
        p[0] = (short)f2bf(a0.x); p[1] = (short)f2bf(a0.y);
        p[2] = (short)f2bf(a1.x); p[3] = (short)f2bf(a1.y);
        p[4] = (short)f2bf(b0.x); p[5] = (short)f2bf(b0.y);
        p[6] = (short)f2bf(b1.x); p[7] = (short)f2bf(b1.y);
#pragma unroll
        for (int nt = 0; nt < 8; ++nt) {
            const short8 wf = *reinterpret_cast<const short8*>(WB + ((nt << 4) + kks) * 512 + lane * 8);
            acc[nt] = __builtin_amdgcn_mfma_f32_16x16x32_bf16(wf, p, acc[nt], 0, 0, 0);
        }
    }

    const int pi = p0 + px;
    ushort_t* op = xm_bf + (size_t)pi * 128;
#pragma unroll
    for (int nt = 0; nt < 8; ++nt) {
        const int ob = nt * 16 + q * 4;
        const float4 s4 = *reinterpret_cast<const float4*>(scr + ob);
        const float4 b4 = *reinterpret_cast<const float4*>(shr + ob);
        const float y0 = siluf_(acc[nt][0] * s4.x + b4.x);
        const float y1 = siluf_(acc[nt][1] * s4.y + b4.y);
        const float y2 = siluf_(acc[nt][2] * s4.z + b4.z);
        const float y3 = siluf_(acc[nt][3] * s4.w + b4.w);
        *reinterpret_cast<uint2*>(op + ob) =
            make_uint2(f2bf(y0) | ((unsigned)f2bf(y1) << 16),
                       f2bf(y2) | ((unsigned)f2bf(y3) << 16));
    }
}

// ---------------------------------------------------------------------------
// k3 v11 FUSED: per-block offset-conv (k2) -> private om in LDS T -> geo ->
// deform-sample + einsum (r14-verbatim inner structure). No om global buffer.
// 512 thr (8 waves), 64 px x 256 o per block. XCD-affine.
// LDS: AS (32KB, A in phase-1 / S in phase-2) + R1 (18KB: T then geoW+geoI)
//      = 50 KB -> 3 blocks/CU.
// ---------------------------------------------------------------------------
__global__ __launch_bounds__(512) void k3_dcn(
    const ushort_t* __restrict__ xm_bf,
    const ushort_t* __restrict__ WoB, const float* __restrict__ obias,
    const ushort_t* __restrict__ WdB,
    const float* __restrict__ g, const float* __restrict__ be,
    const float* __restrict__ mu, const float* __restrict__ va,
    float* __restrict__ out)
{
    __shared__ __align__(16) ushort_t AS[2][64 * 128];  // 32 KB (A then S)
    __shared__ __align__(16) char R1[18432];            // T(8KB) then geo(18KB)
    float*  T    = (float*)R1;                          // [32][64]
    float4* geoWf = (float4*)R1;                        // [9][64]
    int4*   geoIf = (int4*)(R1 + 9216);                 // [9][64]

    const int t    = threadIdx.x;
    const int lane = t & 63;
    const int wave = t >> 6;
    const int p0   = xcd_bid800(blockIdx.x) * 64;
    const int bb   = p0 / HW;
    const int hw0  = p0 % HW;
    const int q = lane >> 4, ln = lane & 15;

    const ushort_t* xb = xm_bf + (size_t)bb * HW * 128;

    // ============ PHASE 1: offset conv (k2) into T ============
    {
        const int spx = t & 63;
        const int hws = hw0 + spx;
        const int hh = hws / WW, wwp = hws % WW;
        const int mt2 = wave & 3;      // M-tile (16 px)
        const int nf2 = wave >> 2;     // o-chunk (0..1)

        auto STAGE2 = [&](int qq, int buf) {
            const int dy = qq / 3 - 1, dx = qq % 3 - 1;
            const int y = hh + dy, xx = wwp + dx;
            const bool valid = ((unsigned)y < 80u) && ((unsigned)xx < 80u);
            const ushort_t* src = xb + ((size_t)(y * WW + xx)) * 128 + wave * 16;
#pragma unroll
            for (int s = 0; s < 2; ++s) {
                uint4 v = make_uint4(0u, 0u, 0u, 0u);
                if (valid) v = *reinterpret_cast<const uint4*>(src + s * 8);
                const int cslot = wave * 2 + s;
                *reinterpret_cast<uint4*>(&AS[buf][spx * 128 + ((cslot ^ (spx & 7)) << 3)]) = v;
            }
        };

        f32x4 acc2 = {};
        auto GEMM2 = [&](int qq, int buf) {
#pragma unroll
            for (int ks = 0; ks < 4; ++ks) {
                const int px = mt2 * 16 + ln;
                const int elem = px * 128 + (((ks * 4 + q) ^ (px & 7)) << 3);
                const short8 a = *reinterpret_cast<const short8*>(&AS[buf][elem]);
                const int chunk = nf2 * 36 + qq * 4 + ks;
                const short8 b = *reinterpret_cast<const short8*>(WoB + chunk * 512 + lane * 8);
                acc2 = __builtin_amdgcn_mfma_f32_16x16x32_bf16(a, b, acc2, 0, 0, 0);
            }
        };

        STAGE2(0, 0);
        __syncthreads();
        for (int qq = 0; qq < 9; ++qq) {
            if (qq < 8) STAGE2(qq + 1, (qq + 1) & 1);
            GEMM2(qq, qq & 1);
            __syncthreads();
        }
        // scatter acc2 -> T[o][px]
#pragma unroll
        for (int r = 0; r < 4; ++r) {
            const int o = nf2 * 16 + ln;
            const int px = mt2 * 16 + q * 4 + r;
            T[o * 64 + px] = acc2[r];
        }
        __syncthreads();
    }

    // ============ PHASE 1.5: geometry from T (overlay-safe) ============
    {
        float goy[2], gox[2], gmk[2];
#pragma unroll
        for (int k2i = 0; k2i < 2; ++k2i) {
            const int it = t + k2i * 512;
            if (it < 576) {
                const int tap = it >> 6, px = it & 63;
                goy[k2i] = T[(2 * tap) * 64 + px] + obias[2 * tap];
                gox[k2i] = T[(2 * tap + 1) * 64 + px] + obias[2 * tap + 1];
                gmk[k2i] = sigmoidf_(T[(18 + tap) * 64 + px] + obias[18 + tap]);
            }
        }
        __syncthreads();   // all T reads done; geo may overwrite R1
#pragma unroll
        for (int k2i = 0; k2i < 2; ++k2i) {
            const int it = t + k2i * 512;
            if (it < 576) {
                const int tap = it >> 6, px = it & 63;
                const int hw = hw0 + px;
                const int h = hw / WW, w = hw % WW;
                float py  = (float)(h - 1 + tap / 3) + goy[k2i];
                float pxf = (float)(w - 1 + tap % 3) + gox[k2i];
                py  = fminf(fmaxf(py, -1000.f), 1000.f);
                pxf = fminf(fmaxf(pxf, -1000.f), 1000.f);
                const float fy = floorf(py), fx = floorf(pxf);
                const int y0 = (int)fy, x0 = (int)fx, y1 = y0 + 1, x1 = x0 + 1;
                const float wy = py - fy, wx = pxf - fx;
                const float vy0 = ((unsigned)y0 < 80u) ? 1.f : 0.f;
                const float vy1 = ((unsigned)y1 < 80u) ? 1.f : 0.f;
                const float vx0 = ((unsigned)x0 < 80u) ? 1.f : 0.f;
                const float vx1 = ((unsigned)x1 < 80u) ? 1.f : 0.f;
                float4 wv;
                const float mk = gmk[k2i];
                wv.x = (1.f - wy) * (1.f - wx) * vy0 * vx0 * mk;
                wv.y = (1.f - wy) * wx * vy0 * vx1 * mk;
                wv.z = wy * (1.f - wx) * vy1 * vx0 * mk;
                wv.w = wy * wx * vy1 * vx1 * mk;
                const int cy0 = min(max(y0, 0), 79), cy1 = min(max(y1, 0), 79);
                const int cx0 = min(max(x0, 0), 79), cx1 = min(max(x1, 0), 79);
                int4 iv;
                iv.x = cy0 * WW + cx0; iv.y = cy0 * WW + cx1;
                iv.z = cy1 * WW + cx0; iv.w = cy1 * WW + cx1;
                geoWf[tap * 64 + px] = wv;
                geoIf[tap * 64 + px] = iv;
            }
        }
        __syncthreads();
    }

    // ============ PHASE 2: deform-sample + einsum (r14 verbatim) ============
    const int spx = t >> 3;
    const int scg = t & 7;
    uint4 pr[8];

    auto ISSUE = [&](int tap) {
        const int4 iv = geoIf[tap * 64 + spx];
        const uint4* c00 = reinterpret_cast<const uint4*>(xb + (size_t)iv.x * 128 + scg * 16);
        const uint4* c01 = reinterpret_cast<const uint4*>(xb + (size_t)iv.y * 128 + scg * 16);
        const uint4* c10 = reinterpret_cast<const uint4*>(xb + (size_t)iv.z * 128 + scg * 16);
        const uint4* c11 = reinterpret_cast<const uint4*>(xb + (size_t)iv.w * 128 + scg * 16);
        pr[0] = c00[0]; pr[1] = c00[1];
        pr[2] = c01[0]; pr[3] = c01[1];
        pr[4] = c10[0]; pr[5] = c10[1];
        pr[6] = c11[0]; pr[7] = c11[1];
    };

    auto BLEND_WRITE = [&](int tap, int bufIdx) {
        const float4 wv = geoWf[tap * 64 + spx];
#pragma unroll
        for (int half = 0; half < 2; ++half) {
            const unsigned* ap = (const unsigned*)&pr[0 + half];
            const unsigned* bp = (const unsigned*)&pr[2 + half];
            const unsigned* cp = (const unsigned*)&pr[4 + half];
            const unsigned* dp = (const unsigned*)&pr[6 + half];
            unsigned pk[4];
#pragma unroll
            for (int u = 0; u < 4; ++u) {
                const float alo = __uint_as_float(ap[u] << 16), ahi = __uint_as_float(ap[u] & 0xFFFF0000u);
                const float blo = __uint_as_float(bp[u] << 16), bhi = __uint_as_float(bp[u] & 0xFFFF0000u);
                const float clo = __uint_as_float(cp[u] << 16), chi = __uint_as_float(cp[u] & 0xFFFF0000u);
                const float dlo = __uint_as_float(dp[u] << 16), dhi = __uint_as_float(dp[u] & 0xFFFF0000u);
                const float slo = wv.x * alo + wv.y * blo + wv.z * clo + wv.w * dlo;
                const float shi = wv.x * ahi + wv.y * bhi + wv.z * chi + wv.w * dhi;
                pk[u] = (unsigned)f2bf(slo) | ((unsigned)f2bf(shi) << 16);
            }
            const int cslot = scg * 2 + half;
            const int elem  = spx * 128 + ((cslot ^ (spx & 7)) << 3);
            *reinterpret_cast<uint4*>(&AS[bufIdx][elem]) =
                make_uint4(pk[0], pk[1], pk[2], pk[3]);
        }
    };

    const int wM = wave >> 2, wN = wave & 3;
    f32x4 acc[2][4] = {};

    auto GEMM = [&](int tap, int bufIdx) {
#pragma unroll
        for (int ks = 0; ks < 4; ++ks) {
            short8 a0, a1;
            {
                const int px = wM * 32 + ln;
                const int elem = px * 128 + (((ks * 4 + q) ^ (px & 7)) << 3);
                a0 = *reinterpret_cast<const short8*>(&AS[bufIdx][elem]);
            }
            {
                const int px = wM * 32 + 16 + ln;
                const int elem = px * 128 + (((ks * 4 + q) ^ (px & 7)) << 3);
                a1 = *reinterpret_cast<const short8*>(&AS[bufIdx][elem]);
            }
#pragma unroll
            for (int nt = 0; nt < 4; ++nt) {
                const int ot = wN * 4 + nt;
                const int chunk = ot * 36 + tap * 4 + ks;
                const short8 b = *reinterpret_cast<const short8*>(WdB + chunk * 512 + lane * 8);
                acc[0][nt] = __builtin_amdgcn_mfma_f32_16x16x32_bf16(a0, b, acc[0][nt], 0, 0, 0);
                acc[1][nt] = __builtin_amdgcn_mfma_f32_16x16x32_bf16(a1, b, acc[1][nt], 0, 0, 0);
            }
        }
    };

    ISSUE(0);
    BLEND_WRITE(0, 0);
    __syncthreads();

    for (int tap = 0; tap < 9; ++tap) {
        if (tap < 8) ISSUE(tap + 1);           // loads in flight across GEMM
        GEMM(tap, tap & 1);
        if (tap < 8) BLEND_WRITE(tap + 1, (tap + 1) & 1);
        __syncthreads();
    }

    float sc[4], sh[4];
#pragma unroll
    for (int nt = 0; nt < 4; ++nt) {
        const int o = wN * 64 + nt * 16 + ln;
        sc[nt] = g[o] * rsqrtf(va[o] + 1e-5f);
        sh[nt] = be[o] - mu[o] * sc[nt];
    }
#pragma unroll
    for (int mt = 0; mt < 2; ++mt)
#pragma unroll
        for (int nt = 0; nt < 4; ++nt) {
            const int o = wN * 64 + nt * 16 + ln;
            float* obase = out + (size_t)bb * 256 * HW + (size_t)o * HW;
            float4 st;
            st.x = siluf_(acc[mt][nt][0] * sc[nt] + sh[nt]);
            st.y = siluf_(acc[mt][nt][1] * sc[nt] + sh[nt]);
            st.z = siluf_(acc[mt][nt][2] * sc[nt] + sh[nt]);
            st.w = siluf_(acc[mt][nt][3] * sc[nt] + sh[nt]);
            *reinterpret_cast<float4*>(obase + hw0 + wM * 32 + mt * 16 + q * 4) = st;
        }
}

// ---------------------------------------------------------------------------
extern "C" void kernel_launch(void* const* d_in, const int* in_sizes, int n_in,
                              void* d_out, int out_size, void* d_ws, size_t ws_size,
                              hipStream_t stream)
{
    const float* x        = (const float*)d_in[0];
    const float* reduce_w = (const float*)d_in[1];
    const float* rg       = (const float*)d_in[2];
    const float* rb       = (const float*)d_in[3];
    const float* rm       = (const float*)d_in[4];
    const float* rv       = (const float*)d_in[5];
    const float* off_w    = (const float*)d_in[6];
    const float* off_b    = (const float*)d_in[7];
    const float* dcn_w    = (const float*)d_in[8];
    const float* dg       = (const float*)d_in[9];
    const float* db       = (const float*)d_in[10];
    const float* dm       = (const float*)d_in[11];
    const float* dv       = (const float*)d_in[12];

    float* ws  = (float*)d_ws;
    ushort_t* xm_bf = (ushort_t*)ws;                 // 6,553,600 bf16
    float* om   = ws + 3276800;                      // (unused now)
    ushort_t* WB   = (ushort_t*)(om + 1382400);      // 65,536 bf16
    ushort_t* WoB  = WB + 65536;                     // 36,864 bf16
    ushort_t* WdB  = WoB + 36864;                    // 294,912 bf16
    float* scr = (float*)(WdB + 294912);             // 128 f
    float* shr = scr + 128;                          // 128 f

    k0_prep<<<dim3(1552), dim3(256), 0, stream>>>(reduce_w, off_w, dcn_w,
                                                  rg, rb, rm, rv,
                                                  WB, WoB, WdB, scr, shr);
    k1_reduce<<<dim3(800), dim3(256), 0, stream>>>(x, WB, scr, shr, xm_bf);
    k3_dcn<<<dim3(800), dim3(512), 0, stream>>>(xm_bf, WoB, off_b, WdB,
                                                dg, db, dm, dv, (float*)d_out);
}

// Round 19
// 157.720 us; speedup vs baseline: 3.3249x; 1.0049x over previous
//
#include <hip/hip_runtime.h>

constexpr int HW  = 6400;   // 80*80
constexpr int WW  = 80;

typedef __attribute__((ext_vector_type(8))) short short8;   // 8 bf16 = 4 VGPR
typedef __attribute__((ext_vector_type(4))) float f32x4;
typedef unsigned short ushort_t;

__device__ __forceinline__ float sigmoidf_(float x) { return 1.f / (1.f + __expf(-x)); }
__device__ __forceinline__ float siluf_(float y) { return y / (1.f + __expf(-y)); }
__device__ __forceinline__ ushort_t f2bf(float f) {   // RNE f32->bf16
    unsigned u = __float_as_uint(f);
    u += 0x7FFFu + ((u >> 16) & 1u);
    return (ushort_t)(u >> 16);
}
__device__ __forceinline__ float bf2f(ushort_t h) {
    return __uint_as_float(((unsigned)h) << 16);
}
// XCD-affinity swizzles (blockIdx lands on XCD b%8, empirical round-robin).
// Verified r14: k3 FETCH_SIZE 40 MB -> 13.6 MB (= exactly one xm read).
__device__ __forceinline__ int xcd_bid800(int b)  { return (b & 7) * 100 + (b >> 3); }
__device__ __forceinline__ int xcd_bid1600(int b) { return (b & 7) * 200 + (b >> 3); }

// ---------------------------------------------------------------------------
// k0: weight prep (bf16 MFMA fragment layouts)
// ---------------------------------------------------------------------------
__global__ __launch_bounds__(256) void k0_prep(
    const float* __restrict__ rw, const float* __restrict__ ow,
    const float* __restrict__ dw,
    const float* __restrict__ rg, const float* __restrict__ rb,
    const float* __restrict__ rm, const float* __restrict__ rv,
    ushort_t* __restrict__ WB,
    ushort_t* __restrict__ WoB, ushort_t* __restrict__ WdB,
    float* __restrict__ scr, float* __restrict__ shr)
{
    const int i = blockIdx.x * 256 + threadIdx.x;
    if (blockIdx.x == 0 && threadIdx.x < 128) {
        const int m = threadIdx.x;
        const float sc = rg[m] * rsqrtf(rv[m] + 1e-5f);
        scr[m] = sc;
        shr[m] = rb[m] - rm[m] * sc;
    }
    if (i < 65536) {                       // WB: 128 chunks * 512
        const int e = i & 7;
        const int lane = (i >> 3) & 63;
        const int chunkW = i >> 9;         // 0..127
        const int nt = chunkW >> 4, kks = chunkW & 15;
        const int kk = kks * 32 + ((lane >> 4) << 3) + e;   // cs 0..511
        const int o = (nt << 4) + (lane & 15);              // out ch 0..127
        WB[i] = f2bf(rw[o * 512 + kk]);
    }
    const int j = i - 65536;
    if (j >= 0 && j < 36864) {             // WoB: 2*36*512
        const int e = j & 7;
        const int lane = (j >> 3) & 63;
        const int chunk = j >> 9;
        const int nf = chunk / 36, ksg = chunk % 36;
        const int kk = ksg * 32 + ((lane >> 4) << 3) + e;
        const int q = kk >> 7, c = kk & 127;
        const int o = (nf << 4) + (lane & 15);
        WoB[j] = (o < 27) ? f2bf(ow[o * 1152 + c * 9 + q]) : (ushort_t)0;
    }
    const int l = j - 36864;
    if (l >= 0 && l < 294912) {            // WdB: 16*36*512
        const int e = l & 7;
        const int lane = (l >> 3) & 63;
        const int chunk = l >> 9;
        const int ot = chunk / 36, ksg = chunk % 36;
        const int kk = ksg * 32 + ((lane >> 4) << 3) + e;
        const int tap = kk >> 7, c = kk & 127;
        const int o = (ot << 4) + (lane & 15);
        WdB[l] = f2bf(dw[o * 1152 + c * 9 + tap]);
    }
}

// ---------------------------------------------------------------------------
// k1 v4: space-to-depth + 1x1 conv as bf16 MFMA, NO LDS. XCD-affine blocks.
// 1600 blocks x 128 thr (2 waves, 32 px/block) — halves the 800-block CU
// quantization tail and doubles block-level latency hiding vs v3.
// ---------------------------------------------------------------------------
__global__ __launch_bounds__(128) void k1_reduce(
    const float* __restrict__ x,
    const ushort_t* __restrict__ WB,
    const float* __restrict__ scr, const float* __restrict__ shr,
    ushort_t* __restrict__ xm_bf)
{
    const int t    = threadIdx.x;
    const int lane = t & 63;
    const int wave = t >> 6;                  // 0..1
    const int q = lane >> 4, ln = lane & 15;
    const int p0 = xcd_bid1600(blockIdx.x) * 32;
    const int bb = p0 / HW;
    const int px = wave * 16 + ln;
    const int hw = (p0 % HW) + px;
    const int h = hw / WW, w = hw % WW;
    const float* xb = x + (size_t)bb * 128 * 25600 + (2 * h) * 160 + 2 * w;

    f32x4 acc[8] = {};

#pragma unroll 4
    for (int kks = 0; kks < 16; ++kks) {
        const int c0 = kks * 8 + q * 2;       // 2 channels per fragment
        const float* pc0 = xb + (size_t)c0 * 25600;
        const float* pc1 = pc0 + 25600;
        const float2 a0 = *reinterpret_cast<const float2*>(pc0);
        const float2 a1 = *reinterpret_cast<const float2*>(pc0 + 160);
        const float2 b0 = *reinterpret_cast<const float2*>(pc1);
        const float2 b1 = *reinterpret_cast<const float2*>(pc1 + 160);
        short8 p;
        p[0] = (short)f2bf(a0.x); p[1] = (short)f2bf(a0.y);
        p[2] = (short)f2bf(a1.x); p[3] = (short)f2bf(a1.y);
        p[4] = (short)f2bf(b0.x); p[5] = (short)f2bf(b0.y);
        p[6] = (short)f2bf(b1.x); p[7] = (short)f2bf(b1.y);
#pragma unroll
        for (int nt = 0; nt < 8; ++nt) {
            const short8 wf = *reinterpret_cast<const short8*>(WB + ((nt << 4) + kks) * 512 + lane * 8);
            acc[nt] = __builtin_amdgcn_mfma_f32_16x16x32_bf16(wf, p, acc[nt], 0, 0, 0);
        }
    }

    const int pi = p0 + px;
    ushort_t* op = xm_bf + (size_t)pi * 128;
#pragma unroll
    for (int nt = 0; nt < 8; ++nt) {
        const int ob = nt * 16 + q * 4;
        const float4 s4 = *reinterpret_cast<const float4*>(scr + ob);
        const float4 b4 = *reinterpret_cast<const float4*>(shr + ob);
        const float y0 = siluf_(acc[nt][0] * s4.x + b4.x);
        const float y1 = siluf_(acc[nt][1] * s4.y + b4.y);
        const float y2 = siluf_(acc[nt][2] * s4.z + b4.z);
        const float y3 = siluf_(acc[nt][3] * s4.w + b4.w);
        *reinterpret_cast<uint2*>(op + ob) =
            make_uint2(f2bf(y0) | ((unsigned)f2bf(y1) << 16),
                       f2bf(y2) | ((unsigned)f2bf(y3) << 16));
    }
}

// ---------------------------------------------------------------------------
// k3 v11 FUSED (r18 verbatim): per-block offset-conv -> om in LDS T -> geo ->
// deform-sample + einsum. 512 thr (8 waves), 64 px x 256 o. XCD-affine.
// ---------------------------------------------------------------------------
__global__ __launch_bounds__(512) void k3_dcn(
    const ushort_t* __restrict__ xm_bf,
    const ushort_t* __restrict__ WoB, const float* __restrict__ obias,
    const ushort_t* __restrict__ WdB,
    const float* __restrict__ g, const float* __restrict__ be,
    const float* __restrict__ mu, const float* __restrict__ va,
    float* __restrict__ out)
{
    __shared__ __align__(16) ushort_t AS[2][64 * 128];  // 32 KB (A then S)
    __shared__ __align__(16) char R1[18432];            // T(8KB) then geo(18KB)
    float*  T    = (float*)R1;                          // [32][64]
    float4* geoWf = (float4*)R1;                        // [9][64]
    int4*   geoIf = (int4*)(R1 + 9216);                 // [9][64]

    const int t    = threadIdx.x;
    const int lane = t & 63;
    const int wave = t >> 6;
    const int p0   = xcd_bid800(blockIdx.x) * 64;
    const int bb   = p0 / HW;
    const int hw0  = p0 % HW;
    const int q = lane >> 4, ln = lane & 15;

    const ushort_t* xb = xm_bf + (size_t)bb * HW * 128;

    // ============ PHASE 1: offset conv (k2) into T ============
    {
        const int spx = t & 63;
        const int hws = hw0 + spx;
        const int hh = hws / WW, wwp = hws % WW;
        const int mt2 = wave & 3;      // M-tile (16 px)
        const int nf2 = wave >> 2;     // o-chunk (0..1)

        auto STAGE2 = [&](int qq, int buf) {
            const int dy = qq / 3 - 1, dx = qq % 3 - 1;
            const int y = hh + dy, xx = wwp + dx;
            const bool valid = ((unsigned)y < 80u) && ((unsigned)xx < 80u);
            const ushort_t* src = xb + ((size_t)(y * WW + xx)) * 128 + wave * 16;
#pragma unroll
            for (int s = 0; s < 2; ++s) {
                uint4 v = make_uint4(0u, 0u, 0u, 0u);
                if (valid) v = *reinterpret_cast<const uint4*>(src + s * 8);
                const int cslot = wave * 2 + s;
                *reinterpret_cast<uint4*>(&AS[buf][spx * 128 + ((cslot ^ (spx & 7)) << 3)]) = v;
            }
        };

        f32x4 acc2 = {};
        auto GEMM2 = [&](int qq, int buf) {
#pragma unroll
            for (int ks = 0; ks < 4; ++ks) {
                const int px = mt2 * 16 + ln;
                const int elem = px * 128 + (((ks * 4 + q) ^ (px & 7)) << 3);
                const short8 a = *reinterpret_cast<const short8*>(&AS[buf][elem]);
                const int chunk = nf2 * 36 + qq * 4 + ks;
                const short8 b = *reinterpret_cast<const short8*>(WoB + chunk * 512 + lane * 8);
                acc2 = __builtin_amdgcn_mfma_f32_16x16x32_bf16(a, b, acc2, 0, 0, 0);
            }
        };

        STAGE2(0, 0);
        __syncthreads();
        for (int qq = 0; qq < 9; ++qq) {
            if (qq < 8) STAGE2(qq + 1, (qq + 1) & 1);
            GEMM2(qq, qq & 1);
            __syncthreads();
        }
        // scatter acc2 -> T[o][px]
#pragma unroll
        for (int r = 0; r < 4; ++r) {
            const int o = nf2 * 16 + ln;
            const int px = mt2 * 16 + q * 4 + r;
            T[o * 64 + px] = acc2[r];
        }
        __syncthreads();
    }

    // ============ PHASE 1.5: geometry from T (overlay-safe) ============
    {
        float goy[2], gox[2], gmk[2];
#pragma unroll
        for (int k2i = 0; k2i < 2; ++k2i) {
            const int it = t + k2i * 512;
            if (it < 576) {
                const int tap = it >> 6, px = it & 63;
                goy[k2i] = T[(2 * tap) * 64 + px] + obias[2 * tap];
                gox[k2i] = T[(2 * tap + 1) * 64 + px] + obias[2 * tap + 1];
                gmk[k2i] = sigmoidf_(T[(18 + tap) * 64 + px] + obias[18 + tap]);
            }
        }
        __syncthreads();   // all T reads done; geo may overwrite R1
#pragma unroll
        for (int k2i = 0; k2i < 2; ++k2i) {
            const int it = t + k2i * 512;
            if (it < 576) {
                const int tap = it >> 6, px = it & 63;
                const int hw = hw0 + px;
                const int h = hw / WW, w = hw % WW;
                float py  = (float)(h - 1 + tap / 3) + goy[k2i];
                float pxf = (float)(w - 1 + tap % 3) + gox[k2i];
                py  = fminf(fmaxf(py, -1000.f), 1000.f);
                pxf = fminf(fmaxf(pxf, -1000.f), 1000.f);
                const float fy = floorf(py), fx = floorf(pxf);
                const int y0 = (int)fy, x0 = (int)fx, y1 = y0 + 1, x1 = x0 + 1;
                const float wy = py - fy, wx = pxf - fx;
                const float vy0 = ((unsigned)y0 < 80u) ? 1.f : 0.f;
                const float vy1 = ((unsigned)y1 < 80u) ? 1.f : 0.f;
                const float vx0 = ((unsigned)x0 < 80u) ? 1.f : 0.f;
                const float vx1 = ((unsigned)x1 < 80u) ? 1.f : 0.f;
                float4 wv;
                const float mk = gmk[k2i];
                wv.x = (1.f - wy) * (1.f - wx) * vy0 * vx0 * mk;
                wv.y = (1.f - wy) * wx * vy0 * vx1 * mk;
                wv.z = wy * (1.f - wx) * vy1 * vx0 * mk;
                wv.w = wy * wx * vy1 * vx1 * mk;
                const int cy0 = min(max(y0, 0), 79), cy1 = min(max(y1, 0), 79);
                const int cx0 = min(max(x0, 0), 79), cx1 = min(max(x1, 0), 79);
                int4 iv;
                iv.x = cy0 * WW + cx0; iv.y = cy0 * WW + cx1;
                iv.z = cy1 * WW + cx0; iv.w = cy1 * WW + cx1;
                geoWf[tap * 64 + px] = wv;
                geoIf[tap * 64 + px] = iv;
            }
        }
        __syncthreads();
    }

    // ============ PHASE 2: deform-sample + einsum (r14 verbatim) ============
    const int spx = t >> 3;
    const int scg = t & 7;
    uint4 pr[8];

    auto ISSUE = [&](int tap) {
        const int4 iv = geoIf[tap * 64 + spx];
        const uint4* c00 = reinterpret_cast<const uint4*>(xb + (size_t)iv.x * 128 + scg * 16);
        const uint4* c01 = reinterpret_cast<const uint4*>(xb + (size_t)iv.y * 128 + scg * 16);
        const uint4* c10 = reinterpret_cast<const uint4*>(xb + (size_t)iv.z * 128 + scg * 16);
        const uint4* c11 = reinterpret_cast<const uint4*>(xb + (size_t)iv.w * 128 + scg * 16);
        pr[0] = c00[0]; pr[1] = c00[1];
        pr[2] = c01[0]; pr[3] = c01[1];
        pr[4] = c10[0]; pr[5] = c10[1];
        pr[6] = c11[0]; pr[7] = c11[1];
    };

    auto BLEND_WRITE = [&](int tap, int bufIdx) {
        const float4 wv = geoWf[tap * 64 + spx];
#pragma unroll
        for (int half = 0; half < 2; ++half) {
            const unsigned* ap = (const unsigned*)&pr[0 + half];
            const unsigned* bp = (const unsigned*)&pr[2 + half];
            const unsigned* cp = (const unsigned*)&pr[4 + half];
            const unsigned* dp = (const unsigned*)&pr[6 + half];
            unsigned pk[4];
#pragma unroll
            for (int u = 0; u < 4; ++u) {
                const float alo = __uint_as_float(ap[u] << 16), ahi = __uint_as_float(ap[u] & 0xFFFF0000u);
                const float blo = __uint_as_float(bp[u] << 16), bhi = __uint_as_float(bp[u] & 0xFFFF0000u);
                const float clo = __uint_as_float(cp[u] << 16), chi = __uint_as_float(cp[u] & 0xFFFF0000u);
                const float dlo = __uint_as_float(dp[u] << 16), dhi = __uint_as_float(dp[u] & 0xFFFF0000u);
                const float slo = wv.x * alo + wv.y * blo + wv.z * clo + wv.w * dlo;
                const float shi = wv.x * ahi + wv.y * bhi + wv.z * chi + wv.w * dhi;
                pk[u] = (unsigned)f2bf(slo) | ((unsigned)f2bf(shi) << 16);
            }
            const int cslot = scg * 2 + half;
            const int elem  = spx * 128 + ((cslot ^ (spx & 7)) << 3);
            *reinterpret_cast<uint4*>(&AS[bufIdx][elem]) =
                make_uint4(pk[0], pk[1], pk[2], pk[3]);
        }
    };

    const int wM = wave >> 2, wN = wave & 3;
    f32x4 acc[2][4] = {};

    auto GEMM = [&](int tap, int bufIdx) {
#pragma unroll
        for (int ks = 0; ks < 4; ++ks) {
            short8 a0, a1;
            {
                const int px = wM * 32 + ln;
                const int elem = px * 128 + (((ks * 4 + q) ^ (px & 7)) << 3);
                a0 = *reinterpret_cast<const short8*>(&AS[bufIdx][elem]);
            }
            {
                const int px = wM * 32 + 16 + ln;
                const int elem = px * 128 + (((ks * 4 + q) ^ (px & 7)) << 3);
                a1 = *reinterpret_cast<const short8*>(&AS[bufIdx][elem]);
            }
#pragma unroll
            for (int nt = 0; nt < 4; ++nt) {
                const int ot = wN * 4 + nt;
                const int chunk = ot * 36 + tap * 4 + ks;
                const short8 b = *reinterpret_cast<const short8*>(WdB + chunk * 512 + lane * 8);
                acc[0][nt] = __builtin_amdgcn_mfma_f32_16x16x32_bf16(a0, b, acc[0][nt], 0, 0, 0);
                acc[1][nt] = __builtin_amdgcn_mfma_f32_16x16x32_bf16(a1, b, acc[1][nt], 0, 0, 0);
            }
        }
    };

    ISSUE(0);
    BLEND_WRITE(0, 0);
    __syncthreads();

    for (int tap = 0; tap < 9; ++tap) {
        if (tap < 8) ISSUE(tap + 1);           // loads in flight across GEMM
        GEMM(tap, tap & 1);
        if (tap < 8) BLEND_WRITE(tap + 1, (tap + 1) & 1);
        __syncthreads();
    }

    float sc[4], sh[4];
#pragma unroll
    for (int nt = 0; nt < 4; ++nt) {
        const int o = wN * 64 + nt * 16 + ln;
        sc[nt] = g[o] * rsqrtf(va[o] + 1e-5f);
        sh[nt] = be[o] - mu[o] * sc[nt];
    }
#pragma unroll
    for (int mt = 0; mt < 2; ++mt)
#pragma unroll
        for (int nt = 0; nt < 4; ++nt) {
            const int o = wN * 64 + nt * 16 + ln;
            float* obase = out + (size_t)bb * 256 * HW + (size_t)o * HW;
            float4 st;
            st.x = siluf_(acc[mt][nt][0] * sc[nt] + sh[nt]);
            st.y = siluf_(acc[mt][nt][1] * sc[nt] + sh[nt]);
            st.z = siluf_(acc[mt][nt][2] * sc[nt] + sh[nt]);
            st.w = siluf_(acc[mt][nt][3] * sc[nt] + sh[nt]);
            *reinterpret_cast<float4*>(obase + hw0 + wM * 32 + mt * 16 + q * 4) = st;
        }
}

// ---------------------------------------------------------------------------
extern "C" void kernel_launch(void* const* d_in, const int* in_sizes, int n_in,
                              void* d_out, int out_size, void* d_ws, size_t ws_size,
                              hipStream_t stream)
{
    const float* x        = (const float*)d_in[0];
    const float* reduce_w = (const float*)d_in[1];
    const float* rg       = (const float*)d_in[2];
    const float* rb       = (const float*)d_in[3];
    const float* rm       = (const float*)d_in[4];
    const float* rv       = (const float*)d_in[5];
    const float* off_w    = (const float*)d_in[6];
    const float* off_b    = (const float*)d_in[7];
    const float* dcn_w    = (const float*)d_in[8];
    const float* dg       = (const float*)d_in[9];
    const float* db       = (const float*)d_in[10];
    const float* dm       = (const float*)d_in[11];
    const float* dv       = (const float*)d_in[12];

    float* ws  = (float*)d_ws;
    ushort_t* xm_bf = (ushort_t*)ws;                 // 6,553,600 bf16
    float* om   = ws + 3276800;                      // (unused now)
    ushort_t* WB   = (ushort_t*)(om + 1382400);      // 65,536 bf16
    ushort_t* WoB  = WB + 65536;                     // 36,864 bf16
    ushort_t* WdB  = WoB + 36864;                    // 294,912 bf16
    float* scr = (float*)(WdB + 294912);             // 128 f
    float* shr = scr + 128;                          // 128 f

    k0_prep<<<dim3(1552), dim3(256), 0, stream>>>(reduce_w, off_w, dcn_w,
                                                  rg, rb, rm, rv,
                                                  WB, WoB, WdB, scr, shr);
    k1_reduce<<<dim3(1600), dim3(128), 0, stream>>>(x, WB, scr, shr, xm_bf);
    k3_dcn<<<dim3(800), dim3(512), 0, stream>>>(xm_bf, WoB, off_b, WdB,
                                                dg, db, dm, dv, (float*)d_out);
}